// Round 8
// baseline (937.621 us; speedup 1.0000x reference)
//
#include <hip/hip_runtime.h>
#include <stdint.h>

#define NROW 8192
#define LOG2E 1.4426950408889634f
#define ALPHA 0.3f

// workspace float-index offsets
#define WA1_OFF 0
#define WA2_OFF 512
#define S1_OFF 1024
#define S2_OFF (1024 + 8192)
#define SCAL_OFF (S2_OFF + 8192)
// workspace byte offsets
#define PQB_OFF 70656                 // 16B-aligned, past scalars
#define PQB_BYTES (256 * 40960)       // 256 k-blocks x [2][320 cols][32 k] f16
#define AMSK_OFF (PQB_OFF + PQB_BYTES)
#define AMSK_BYTES (NROW * 256 * 4)   // 8 MB bitmask: [row][256 words]
#define WTF_OFF (AMSK_OFF + AMSK_BYTES)
#define WTF_BYTES (10 * 40960)        // 10 k-tiles x [2][320 cols][32 c] f16
#define PART_OFF (WTF_OFF + WTF_BYTES)

typedef _Float16 f16x8 __attribute__((ext_vector_type(8)));
typedef __fp16 fp16x2 __attribute__((ext_vector_type(2)));
typedef float f32x4 __attribute__((ext_vector_type(4)));

union HPack { fp16x2 h2[4]; f16x8 v; uint32_t u[4]; };
union PkU { fp16x2 p; uint32_t u; };

__device__ __forceinline__ int swz(int col, int g) { return (g + (col >> 1)) & 3; }

// ---------------- K0: wa1/wa2 = W @ a halves (wave-per-row dot) ----------------
__global__ void k_wa(const float* __restrict__ Wm, const float* __restrict__ a,
                     float* __restrict__ wsf) {
  int r = blockIdx.x * 4 + (threadIdx.x >> 6);
  int ln = threadIdx.x & 63;
  if (r >= 300) return;
  float a1 = 0.f, a2 = 0.f;
  for (int c = ln; c < 300; c += 64) {
    float w = Wm[r * 300 + c];
    a1 += w * a[c];
    a2 += w * a[300 + c];
  }
  for (int o = 32; o; o >>= 1) { a1 += __shfl_down(a1, o); a2 += __shfl_down(a2, o); }
  if (!ln) { wsf[WA1_OFF + r] = a1; wsf[WA2_OFF + r] = a2; }
}

// ---------------- K1: s1/s2 = inp @ wa (scaled by log2e) ----------------
__global__ void k_s12(const float* __restrict__ inp, float* __restrict__ wsf) {
  int row = blockIdx.x * 4 + (threadIdx.x >> 6);
  int ln = threadIdx.x & 63;
  const float* ip = inp + (size_t)row * 300;
  float a1 = 0.f, a2 = 0.f;
  for (int c = ln; c < 300; c += 64) {
    float v = ip[c];
    a1 += v * wsf[WA1_OFF + c];
    a2 += v * wsf[WA2_OFF + c];
  }
  for (int o = 32; o; o >>= 1) { a1 += __shfl_down(a1, o); a2 += __shfl_down(a2, o); }
  if (!ln) { wsf[S1_OFF + row] = a1 * LOG2E; wsf[S2_OFF + row] = a2 * LOG2E; }
}

// ---------------- K2: global max/min of s2' ----------------
__global__ void k_minmax(float* __restrict__ wsf) {
  int t = threadIdx.x;
  float mx = -3e38f, mn = 3e38f;
  for (int i = t; i < NROW; i += 1024) {
    float v = wsf[S2_OFF + i];
    mx = fmaxf(mx, v); mn = fminf(mn, v);
  }
  for (int o = 32; o; o >>= 1) {
    mx = fmaxf(mx, __shfl_down(mx, o));
    mn = fminf(mn, __shfl_down(mn, o));
  }
  __shared__ float sm[32];
  int wv = t >> 6, ln = t & 63;
  if (!ln) { sm[wv] = mx; sm[16 + wv] = mn; }
  __syncthreads();
  if (!t) {
    float M = sm[0], m = sm[16];
    for (int q = 1; q < 16; q++) { M = fmaxf(M, sm[q]); m = fminf(m, sm[16 + q]); }
    wsf[SCAL_OFF] = M; wsf[SCAL_OFF + 1] = m;
  }
}

// ---------------- K2a: wtrans f32 -> f16 tiles in swizzled B layout ----------------
__global__ __launch_bounds__(320) void k_wprep(const float* __restrict__ wt,
                                               uint16_t* __restrict__ wtf) {
  const int t = blockIdx.x >> 1;
  const int pq = blockIdx.x & 1;
  const int col = threadIdx.x;  // 0..319
  uint16_t* dst = wtf + (size_t)t * 20480 + pq * 10240 + col * 32;
  #pragma unroll
  for (int g = 0; g < 4; g++) {
    const int gs = swz(col, g);
    uint32_t* d32 = (uint32_t*)(dst + gs * 8);
    #pragma unroll
    for (int jj = 0; jj < 4; jj++) {
      const int c0 = t * 32 + g * 8 + 2 * jj;
      float v0 = (col < 300 && c0 < 300) ? wt[(size_t)(pq * 300 + c0) * 300 + col] : 0.f;
      float v1 = (col < 300 && c0 + 1 < 300) ? wt[(size_t)(pq * 300 + c0 + 1) * 300 + col] : 0.f;
      PkU pk; pk.p = __builtin_amdgcn_cvt_pkrtz(v0, v1);
      d32[jj] = pk.u;
    }
  }
}

// ---------------- K3: fused {wt-role: P/Q = inp @ wtrans via MFMA} + {pack-role} ----
#define WT_BLOCKS 256
__global__ __launch_bounds__(640) void k_packwt(const int* __restrict__ adj,
                                                uint32_t* __restrict__ amask,
                                                const float* __restrict__ inp,
                                                const uint16_t* __restrict__ wtf,
                                                uint16_t* __restrict__ pqb) {
  __shared__ __align__(16) uint16_t W2[2][20480];
  const int bid = blockIdx.x;
  const int tid = threadIdx.x;
  if (bid >= WT_BLOCKS) {
    const size_t wd = (size_t)(bid - WT_BLOCKS) * 640 + tid;
    if (wd < (size_t)NROW * 256) {
      const int4* src = (const int4*)(adj + wd * 32);
      uint32_t m = 0;
      #pragma unroll
      for (int j = 0; j < 8; j++) {
        int4 v = src[j];
        m |= (v.x ? 1u : 0u) << (4 * j);
        m |= (v.y ? 1u : 0u) << (4 * j + 1);
        m |= (v.z ? 1u : 0u) << (4 * j + 2);
        m |= (v.w ? 1u : 0u) << (4 * j + 3);
      }
      amask[wd] = m;
    }
    return;
  }
  // ---- wt role ----
  const int kb = bid;
  const int w = tid >> 6, lane = tid & 63;
  const int lr = lane & 15, lg = lane >> 4;
  const int side = (w >= 5) ? 1 : 0;
  const int w5 = w - side * 5;
  f32x4 acc[2][4];
  const f32x4 zero = {0.f, 0.f, 0.f, 0.f};
  #pragma unroll
  for (int fr = 0; fr < 2; fr++)
    #pragma unroll
    for (int i = 0; i < 4; i++) acc[fr][i] = zero;

  auto STAGE = [&](int b, int t) {
    const char* tile = (const char*)wtf + (size_t)t * 40960;
    char* dst = (char*)W2[b];
    #pragma unroll
    for (int it = 0; it < 4; it++) {
      const int off = (w * 4 + it) * 1024;
      __builtin_amdgcn_global_load_lds(
          (const __attribute__((address_space(1))) void*)(tile + off + lane * 16),
          (__attribute__((address_space(3))) void*)(dst + off),
          16, 0, 0);
    }
  };

  const float* arow0 = inp + (size_t)(kb * 32 + lr) * 300;
  const float* arow1 = inp + (size_t)(kb * 32 + 16 + lr) * 300;

  STAGE(0, 0);
  __syncthreads();
  for (int t = 0; t < 10; t++) {
    if (t < 9) STAGE((t + 1) & 1, t + 1);
    const int c = t * 32 + lg * 8;
    float4 z4 = {0.f, 0.f, 0.f, 0.f};
    float4 a0l = z4, a0h = z4, a1l = z4, a1h = z4;
    if (c <= 296) { a0l = *(const float4*)(arow0 + c); a1l = *(const float4*)(arow1 + c); }
    if (c <= 292) { a0h = *(const float4*)(arow0 + c + 4); a1h = *(const float4*)(arow1 + c + 4); }
    HPack A0, A1;
    A0.h2[0] = __builtin_amdgcn_cvt_pkrtz(a0l.x, a0l.y);
    A0.h2[1] = __builtin_amdgcn_cvt_pkrtz(a0l.z, a0l.w);
    A0.h2[2] = __builtin_amdgcn_cvt_pkrtz(a0h.x, a0h.y);
    A0.h2[3] = __builtin_amdgcn_cvt_pkrtz(a0h.z, a0h.w);
    A1.h2[0] = __builtin_amdgcn_cvt_pkrtz(a1l.x, a1l.y);
    A1.h2[1] = __builtin_amdgcn_cvt_pkrtz(a1l.z, a1l.w);
    A1.h2[2] = __builtin_amdgcn_cvt_pkrtz(a1h.x, a1h.y);
    A1.h2[3] = __builtin_amdgcn_cvt_pkrtz(a1h.z, a1h.w);
    const char* half = (const char*)W2[t & 1] + side * 20480;
    #pragma unroll
    for (int i = 0; i < 4; i++) {
      const int f = w5 * 4 + i;
      if (f < 19) {
        const int col = f * 16 + lr;
        f16x8 b = *(const f16x8*)(half + col * 64 + swz(col, lg) * 16);
        acc[0][i] = __builtin_amdgcn_mfma_f32_16x16x32_f16(A0.v, b, acc[0][i], 0, 0, 0);
        acc[1][i] = __builtin_amdgcn_mfma_f32_16x16x32_f16(A1.v, b, acc[1][i], 0, 0, 0);
      }
    }
    __syncthreads();
  }
  // epilogue: write pqb in k_main's layout
  uint16_t* outb = pqb + (size_t)kb * 20480 + side * 10240;
  #pragma unroll
  for (int i = 0; i < 4; i++) {
    const int f = w5 * 4 + i;
    if (f >= 19) continue;
    const int col = f * 16 + lr;
    #pragma unroll
    for (int fr = 0; fr < 2; fr++) {
      float v0 = acc[fr][i][0], v1 = acc[fr][i][1], v2 = acc[fr][i][2], v3 = acc[fr][i][3];
      if (col == 300) { v0 = v1 = v2 = v3 = 1.0f; }
      else if (col > 300) { v0 = v1 = v2 = v3 = 0.0f; }
      const int g = fr * 2 + (lg >> 1);
      uint32_t* dst = (uint32_t*)(outb + col * 32 + swz(col, g) * 8 + (lg & 1) * 4);
      PkU p0; p0.p = __builtin_amdgcn_cvt_pkrtz(v0, v1);
      PkU p1; p1.p = __builtin_amdgcn_cvt_pkrtz(v2, v3);
      dst[0] = p0.u;
      dst[1] = p1.u;
    }
  }
}

// ---------------- K4: fused masked-double-softmax @ [P|Q] ----------------
// 2-buffer LDS (80 KB) + counted vmcnt(4) -> 2 blocks/CU, 16 waves/CU (4/SIMD).
// 512 threads / 8 waves / 128 rows per block; wave = 2 row-frags x 1 side.
// Per-iter VMEM = 9/wave: regs(4) + STAGE(5). vmcnt(4) certifies STAGE(s)
// complete while regs(s+1) stay in flight; STAGE(s+1) issued right after the
// barrier gets a full compute body to land.
__global__ __launch_bounds__(512, 4) void k_main(const uint32_t* __restrict__ amask,
                                                 const float* __restrict__ wsf,
                                                 const uint16_t* __restrict__ pqb,
                                                 float* __restrict__ part, int nsplit) {
  __shared__ __align__(16) uint16_t Bsm[2][20480];  // 2 x 40960 B = 80 KB
  const int bid = blockIdx.x;
  const int mblk = bid / nsplit;
  const int ks = bid - mblk * nsplit;
  const int tid = threadIdx.x;
  const int w = tid >> 6, lane = tid & 63;
  const int lr = lane & 15, lg = lane >> 4;
  const int side = w & 1;      // 0 = positive softmax, 1 = negative
  const int rg = w >> 1;       // row group (0..3)
  const int rbase = mblk * 128 + rg * 32;
  const int row0 = rbase + lr;
  const int row1 = rbase + 16 + lr;
  const float c1_0 = wsf[S1_OFF + row0];
  const float c1_1 = wsf[S1_OFF + row1];
  const float s2ref = side ? wsf[SCAL_OFF + 1] : wsf[SCAL_OFF];
  const float sgn = side ? -1.0f : 1.0f;
  float tt0 = c1_0 + s2ref; const float so0 = sgn * fmaxf(tt0, ALPHA * tt0);
  float tt1 = c1_1 + s2ref; const float so1 = sgn * fmaxf(tt1, ALPHA * tt1);
  const int kcnt = NROW / nsplit;
  const int k0 = ks * kcnt;
  const int ksteps = kcnt >> 5;
  const int tb0 = k0 >> 5;
  const uint32_t* mr0 = amask + (size_t)row0 * 256;
  const uint32_t* mr1 = amask + (size_t)row1 * 256;
  f32x4 acc0[19], acc1[19];
  const f32x4 zero = {0.f, 0.f, 0.f, 0.f};
  #pragma unroll
  for (int ct = 0; ct < 19; ct++) { acc0[ct] = zero; acc1[ct] = zero; }

  auto STAGE = [&](int b, int tb) {   // 5 x 1KB global_load_lds per wave
    const char* tile = (const char*)(pqb + (size_t)tb * 20480);
    char* dst = (char*)Bsm[b];
    #pragma unroll
    for (int it = 0; it < 5; it++) {
      const int off = (w * 5 + it) * 1024;
      __builtin_amdgcn_global_load_lds(
          (const __attribute__((address_space(1))) void*)(tile + off + lane * 16),
          (__attribute__((address_space(3))) void*)(dst + off),
          16, 0, 0);
    }
  };

  // prologue: STAGE(0), regs(0)
  STAGE(0, tb0);
  uint32_t cM0 = mr0[tb0];
  uint32_t cM1 = mr1[tb0];
  const int kw0 = k0 + lg * 8;
  float4 cS0 = *(const float4*)(wsf + S2_OFF + kw0);
  float4 cS1 = *(const float4*)(wsf + S2_OFF + kw0 + 4);

  for (int s = 0; s < ksteps; s++) {
    // B: prefetch regs for step s+1 (clamped) -- 4 VMEM ops
    const int sp = (s + 1 < ksteps) ? s + 1 : s;
    const uint32_t nM0 = mr0[tb0 + sp];
    const uint32_t nM1 = mr1[tb0 + sp];
    const int kwn = k0 + sp * 32 + lg * 8;
    const float4 nS0 = *(const float4*)(wsf + S2_OFF + kwn);
    const float4 nS1 = *(const float4*)(wsf + S2_OFF + kwn + 4);

    // certify STAGE(s)+regs(s) complete; regs(s+1) stay in flight
    asm volatile("s_waitcnt vmcnt(4)" ::: "memory");
    __builtin_amdgcn_sched_barrier(0);
    __builtin_amdgcn_s_barrier();   // buf[s&1] fully written; buf[(s+1)&1] reads done

    // A: stage tile s+1 into buf[(s+1)&1] -- 5 VMEM ops (lands during compute)
    STAGE((s + 1) & 1, tb0 + sp);

    // C: exp/mask/pack for current step (register-only inputs)
    float se[8] = {cS0.x, cS0.y, cS0.z, cS0.w, cS1.x, cS1.y, cS1.z, cS1.w};
    const uint32_t b0 = (cM0 >> (lg * 8)) & 0xffu;
    const uint32_t b1 = (cM1 >> (lg * 8)) & 0xffu;
    HPack up0, up1;
    #pragma unroll
    for (int e = 0; e < 8; e += 2) {
      float e0a = c1_0 + se[e];     e0a = fmaxf(e0a, ALPHA * e0a);
      float e0b = c1_0 + se[e + 1]; e0b = fmaxf(e0b, ALPHA * e0b);
      float e1a = c1_1 + se[e];     e1a = fmaxf(e1a, ALPHA * e1a);
      float e1b = c1_1 + se[e + 1]; e1b = fmaxf(e1b, ALPHA * e1b);
      float p0a = exp2f(__builtin_fmaf(sgn, e0a, -so0)); p0a = (b0 & (1u << e)) ? p0a : 0.0f;
      float p0b = exp2f(__builtin_fmaf(sgn, e0b, -so0)); p0b = (b0 & (2u << e)) ? p0b : 0.0f;
      float p1a = exp2f(__builtin_fmaf(sgn, e1a, -so1)); p1a = (b1 & (1u << e)) ? p1a : 0.0f;
      float p1b = exp2f(__builtin_fmaf(sgn, e1b, -so1)); p1b = (b1 & (2u << e)) ? p1b : 0.0f;
      up0.h2[e >> 1] = __builtin_amdgcn_cvt_pkrtz(p0a, p0b);
      up1.h2[e >> 1] = __builtin_amdgcn_cvt_pkrtz(p1a, p1b);
    }

    const char* half = (const char*)Bsm[s & 1] + side * 20480;
    __builtin_amdgcn_s_setprio(1);
    #pragma unroll
    for (int ct = 0; ct < 19; ct++) {
      const int col = ct * 16 + lr;
      const int gp = swz(col, lg);
      f16x8 b = *(const f16x8*)(half + col * 64 + gp * 16);
      acc0[ct] = __builtin_amdgcn_mfma_f32_16x16x32_f16(up0.v, b, acc0[ct], 0, 0, 0);
      acc1[ct] = __builtin_amdgcn_mfma_f32_16x16x32_f16(up1.v, b, acc1[ct], 0, 0, 0);
    }
    __builtin_amdgcn_s_setprio(0);

    cM0 = nM0; cM1 = nM1; cS0 = nS0; cS1 = nS1;
  }

  // C/D layout: col = lane&15, row = lg*4 + reg (per frag)
  float* pb = part + ((size_t)ks * NROW + rbase) * 608 + (size_t)side * 304;
  #pragma unroll
  for (int ct = 0; ct < 19; ct++) {
    const int col = ct * 16 + lr;
    #pragma unroll
    for (int r = 0; r < 4; r++) {
      pb[(size_t)(lg * 4 + r) * 608 + col] = acc0[ct][r];
      pb[(size_t)(16 + lg * 4 + r) * 608 + col] = acc1[ct][r];
    }
  }
}

// ---------------- K5: reduce k-splits, normalize, elu ----------------
__global__ void k_final(const float* __restrict__ part, float* __restrict__ out, int nsplit) {
  const int i = blockIdx.x;
  const int t = threadIdx.x;
  if (t >= 300) return;
  float sp = 0.f, sn = 0.f, zp = 0.f, zn = 0.f;
  for (int s = 0; s < nsplit; s++) {
    const float* p = part + ((size_t)s * NROW + i) * 608;
    sp += p[t];
    sn += p[304 + t];
    zp += p[300];
    zn += p[604];
  }
  float x = sp / zp - sn / zn;
  out[(size_t)i * 300 + t] = (x > 0.f) ? x : (exp2f(x * LOG2E) - 1.0f);
}

extern "C" void kernel_launch(void* const* d_in, const int* in_sizes, int n_in,
                              void* d_out, int out_size, void* d_ws, size_t ws_size,
                              hipStream_t stream) {
  const float* inp = (const float*)d_in[0];
  const int* adj = (const int*)d_in[1];
  const float* Wm = (const float*)d_in[2];
  const float* a = (const float*)d_in[3];
  const float* wt = (const float*)d_in[4];
  float* out = (float*)d_out;
  float* wsf = (float*)d_ws;
  uint16_t* pqb = (uint16_t*)((char*)d_ws + PQB_OFF);
  uint32_t* amask = (uint32_t*)((char*)d_ws + AMSK_OFF);
  uint16_t* wtf = (uint16_t*)((char*)d_ws + WTF_OFF);
  float* part = (float*)((char*)d_ws + PART_OFF);

  int nsplit = 8;
  while (nsplit > 1 &&
         (size_t)PART_OFF + (size_t)nsplit * NROW * 608 * 4 > ws_size)
    nsplit >>= 1;

  const int pack_blocks = (NROW * 256 + 639) / 640;
  k_wa<<<75, 256, 0, stream>>>(Wm, a, wsf);
  k_wprep<<<20, 320, 0, stream>>>(wt, wtf);
  k_s12<<<NROW / 4, 256, 0, stream>>>(inp, wsf);
  k_minmax<<<1, 1024, 0, stream>>>(wsf);
  k_packwt<<<WT_BLOCKS + pack_blocks, 640, 0, stream>>>(adj, amask, inp, wtf, pqb);
  k_main<<<64 * nsplit, 512, 0, stream>>>(amask, wsf, pqb, part, nsplit);
  k_final<<<NROW, 320, 0, stream>>>(part, out, nsplit);
}

// Round 9
// 231.554 us; speedup vs baseline: 4.0493x; 4.0493x over previous
//
#include <hip/hip_runtime.h>
#include <stdint.h>

#define NROW 8192
#define LOG2E 1.4426950408889634f
#define ALPHA 0.3f

// workspace float-index offsets
#define WA1_OFF 0
#define WA2_OFF 512
#define S1_OFF 1024
#define S2_OFF (1024 + 8192)
#define SCAL_OFF (S2_OFF + 8192)
// workspace byte offsets
#define PQB_OFF 70656                 // 16B-aligned, past scalars
#define PQB_BYTES (256 * 40960)       // 256 k-blocks x [2][320 cols][32 k] f16
#define AMSK_OFF (PQB_OFF + PQB_BYTES)
#define AMSK_BYTES (NROW * 256 * 4)   // 8 MB bitmask: [row][256 words]
#define WTF_OFF (AMSK_OFF + AMSK_BYTES)
#define WTF_BYTES (10 * 40960)        // 10 k-tiles x [2][320 cols][32 c] f16
#define PART_OFF (WTF_OFF + WTF_BYTES)

typedef _Float16 f16x8 __attribute__((ext_vector_type(8)));
typedef __fp16 fp16x2 __attribute__((ext_vector_type(2)));
typedef float f32x4 __attribute__((ext_vector_type(4)));

union HPack { fp16x2 h2[4]; f16x8 v; uint32_t u[4]; };
union PkU { fp16x2 p; uint32_t u; };

__device__ __forceinline__ int swz(int col, int g) { return (g + (col >> 1)) & 3; }

// ---------------- K0: wa1/wa2 = W @ a halves (wave-per-row dot) ----------------
__global__ void k_wa(const float* __restrict__ Wm, const float* __restrict__ a,
                     float* __restrict__ wsf) {
  int r = blockIdx.x * 4 + (threadIdx.x >> 6);
  int ln = threadIdx.x & 63;
  if (r >= 300) return;
  float a1 = 0.f, a2 = 0.f;
  for (int c = ln; c < 300; c += 64) {
    float w = Wm[r * 300 + c];
    a1 += w * a[c];
    a2 += w * a[300 + c];
  }
  for (int o = 32; o; o >>= 1) { a1 += __shfl_down(a1, o); a2 += __shfl_down(a2, o); }
  if (!ln) { wsf[WA1_OFF + r] = a1; wsf[WA2_OFF + r] = a2; }
}

// ---------------- K1: s1/s2 = inp @ wa (scaled by log2e) ----------------
__global__ void k_s12(const float* __restrict__ inp, float* __restrict__ wsf) {
  int row = blockIdx.x * 4 + (threadIdx.x >> 6);
  int ln = threadIdx.x & 63;
  const float* ip = inp + (size_t)row * 300;
  float a1 = 0.f, a2 = 0.f;
  for (int c = ln; c < 300; c += 64) {
    float v = ip[c];
    a1 += v * wsf[WA1_OFF + c];
    a2 += v * wsf[WA2_OFF + c];
  }
  for (int o = 32; o; o >>= 1) { a1 += __shfl_down(a1, o); a2 += __shfl_down(a2, o); }
  if (!ln) { wsf[S1_OFF + row] = a1 * LOG2E; wsf[S2_OFF + row] = a2 * LOG2E; }
}

// ---------------- K2: global max/min of s2' ----------------
__global__ void k_minmax(float* __restrict__ wsf) {
  int t = threadIdx.x;
  float mx = -3e38f, mn = 3e38f;
  for (int i = t; i < NROW; i += 1024) {
    float v = wsf[S2_OFF + i];
    mx = fmaxf(mx, v); mn = fminf(mn, v);
  }
  for (int o = 32; o; o >>= 1) {
    mx = fmaxf(mx, __shfl_down(mx, o));
    mn = fminf(mn, __shfl_down(mn, o));
  }
  __shared__ float sm[32];
  int wv = t >> 6, ln = t & 63;
  if (!ln) { sm[wv] = mx; sm[16 + wv] = mn; }
  __syncthreads();
  if (!t) {
    float M = sm[0], m = sm[16];
    for (int q = 1; q < 16; q++) { M = fmaxf(M, sm[q]); m = fminf(m, sm[16 + q]); }
    wsf[SCAL_OFF] = M; wsf[SCAL_OFF + 1] = m;
  }
}

// ---------------- K2a: wtrans f32 -> f16 tiles in swizzled B layout ----------------
__global__ __launch_bounds__(320) void k_wprep(const float* __restrict__ wt,
                                               uint16_t* __restrict__ wtf) {
  const int t = blockIdx.x >> 1;
  const int pq = blockIdx.x & 1;
  const int col = threadIdx.x;  // 0..319
  uint16_t* dst = wtf + (size_t)t * 20480 + pq * 10240 + col * 32;
  #pragma unroll
  for (int g = 0; g < 4; g++) {
    const int gs = swz(col, g);
    uint32_t* d32 = (uint32_t*)(dst + gs * 8);
    #pragma unroll
    for (int jj = 0; jj < 4; jj++) {
      const int c0 = t * 32 + g * 8 + 2 * jj;
      float v0 = (col < 300 && c0 < 300) ? wt[(size_t)(pq * 300 + c0) * 300 + col] : 0.f;
      float v1 = (col < 300 && c0 + 1 < 300) ? wt[(size_t)(pq * 300 + c0 + 1) * 300 + col] : 0.f;
      PkU pk; pk.p = __builtin_amdgcn_cvt_pkrtz(v0, v1);
      d32[jj] = pk.u;
    }
  }
}

// ---------------- K3: fused {wt-role: P/Q = inp @ wtrans via MFMA} + {pack-role} ----
#define WT_BLOCKS 256
__global__ __launch_bounds__(640) void k_packwt(const int* __restrict__ adj,
                                                uint32_t* __restrict__ amask,
                                                const float* __restrict__ inp,
                                                const uint16_t* __restrict__ wtf,
                                                uint16_t* __restrict__ pqb) {
  __shared__ __align__(16) uint16_t W2[2][20480];
  const int bid = blockIdx.x;
  const int tid = threadIdx.x;
  if (bid >= WT_BLOCKS) {
    const size_t wd = (size_t)(bid - WT_BLOCKS) * 640 + tid;
    if (wd < (size_t)NROW * 256) {
      const int4* src = (const int4*)(adj + wd * 32);
      uint32_t m = 0;
      #pragma unroll
      for (int j = 0; j < 8; j++) {
        int4 v = src[j];
        m |= (v.x ? 1u : 0u) << (4 * j);
        m |= (v.y ? 1u : 0u) << (4 * j + 1);
        m |= (v.z ? 1u : 0u) << (4 * j + 2);
        m |= (v.w ? 1u : 0u) << (4 * j + 3);
      }
      amask[wd] = m;
    }
    return;
  }
  // ---- wt role ----
  const int kb = bid;
  const int w = tid >> 6, lane = tid & 63;
  const int lr = lane & 15, lg = lane >> 4;
  const int side = (w >= 5) ? 1 : 0;
  const int w5 = w - side * 5;
  f32x4 acc[2][4];
  const f32x4 zero = {0.f, 0.f, 0.f, 0.f};
  #pragma unroll
  for (int fr = 0; fr < 2; fr++)
    #pragma unroll
    for (int i = 0; i < 4; i++) acc[fr][i] = zero;

  auto STAGE = [&](int b, int t) {
    const char* tile = (const char*)wtf + (size_t)t * 40960;
    char* dst = (char*)W2[b];
    #pragma unroll
    for (int it = 0; it < 4; it++) {
      const int off = (w * 4 + it) * 1024;
      __builtin_amdgcn_global_load_lds(
          (const __attribute__((address_space(1))) void*)(tile + off + lane * 16),
          (__attribute__((address_space(3))) void*)(dst + off),
          16, 0, 0);
    }
  };

  const float* arow0 = inp + (size_t)(kb * 32 + lr) * 300;
  const float* arow1 = inp + (size_t)(kb * 32 + 16 + lr) * 300;

  STAGE(0, 0);
  __syncthreads();
  for (int t = 0; t < 10; t++) {
    if (t < 9) STAGE((t + 1) & 1, t + 1);
    const int c = t * 32 + lg * 8;
    float4 z4 = {0.f, 0.f, 0.f, 0.f};
    float4 a0l = z4, a0h = z4, a1l = z4, a1h = z4;
    if (c <= 296) { a0l = *(const float4*)(arow0 + c); a1l = *(const float4*)(arow1 + c); }
    if (c <= 292) { a0h = *(const float4*)(arow0 + c + 4); a1h = *(const float4*)(arow1 + c + 4); }
    HPack A0, A1;
    A0.h2[0] = __builtin_amdgcn_cvt_pkrtz(a0l.x, a0l.y);
    A0.h2[1] = __builtin_amdgcn_cvt_pkrtz(a0l.z, a0l.w);
    A0.h2[2] = __builtin_amdgcn_cvt_pkrtz(a0h.x, a0h.y);
    A0.h2[3] = __builtin_amdgcn_cvt_pkrtz(a0h.z, a0h.w);
    A1.h2[0] = __builtin_amdgcn_cvt_pkrtz(a1l.x, a1l.y);
    A1.h2[1] = __builtin_amdgcn_cvt_pkrtz(a1l.z, a1l.w);
    A1.h2[2] = __builtin_amdgcn_cvt_pkrtz(a1h.x, a1h.y);
    A1.h2[3] = __builtin_amdgcn_cvt_pkrtz(a1h.z, a1h.w);
    const char* half = (const char*)W2[t & 1] + side * 20480;
    #pragma unroll
    for (int i = 0; i < 4; i++) {
      const int f = w5 * 4 + i;
      if (f < 19) {
        const int col = f * 16 + lr;
        f16x8 b = *(const f16x8*)(half + col * 64 + swz(col, lg) * 16);
        acc[0][i] = __builtin_amdgcn_mfma_f32_16x16x32_f16(A0.v, b, acc[0][i], 0, 0, 0);
        acc[1][i] = __builtin_amdgcn_mfma_f32_16x16x32_f16(A1.v, b, acc[1][i], 0, 0, 0);
      }
    }
    __syncthreads();
  }
  // epilogue: write pqb in k_main's layout
  uint16_t* outb = pqb + (size_t)kb * 20480 + side * 10240;
  #pragma unroll
  for (int i = 0; i < 4; i++) {
    const int f = w5 * 4 + i;
    if (f >= 19) continue;
    const int col = f * 16 + lr;
    #pragma unroll
    for (int fr = 0; fr < 2; fr++) {
      float v0 = acc[fr][i][0], v1 = acc[fr][i][1], v2 = acc[fr][i][2], v3 = acc[fr][i][3];
      if (col == 300) { v0 = v1 = v2 = v3 = 1.0f; }
      else if (col > 300) { v0 = v1 = v2 = v3 = 0.0f; }
      const int g = fr * 2 + (lg >> 1);
      uint32_t* dst = (uint32_t*)(outb + col * 32 + swz(col, g) * 8 + (lg & 1) * 4);
      PkU p0; p0.p = __builtin_amdgcn_cvt_pkrtz(v0, v1);
      PkU p1; p1.p = __builtin_amdgcn_cvt_pkrtz(v2, v3);
      dst[0] = p0.u;
      dst[1] = p1.u;
    }
  }
}

// ---------------- K4: fused masked-double-softmax @ [P|Q] ----------------
// 256 threads / 4 waves / 64 rows per block, 2-buffer LDS (80 KB) ->
// TWO independent blocks per CU (160 KB exact): when one block sits at its
// barrier/vmcnt, the other block's waves keep the pipes fed.
// Counted vmcnt: per-iter VMEM = regs(4) + STAGE(10). vmcnt(4) certifies
// STAGE(s)+regs(s) done while regs(s+1) stay in flight; STAGE(s+1) issued
// right after the barrier lands during the compute body.
__global__ __launch_bounds__(256, 2) void k_main(const uint32_t* __restrict__ amask,
                                                 const float* __restrict__ wsf,
                                                 const uint16_t* __restrict__ pqb,
                                                 float* __restrict__ part, int nsplit) {
  __shared__ __align__(16) uint16_t Bsm[2][20480];  // 2 x 40960 B = 80 KB
  const int bid = blockIdx.x;
  const int mblk = bid / nsplit;
  const int ks = bid - mblk * nsplit;
  const int tid = threadIdx.x;
  const int w = tid >> 6, lane = tid & 63;
  const int lr = lane & 15, lg = lane >> 4;
  const int side = w & 1;      // 0 = positive softmax, 1 = negative
  const int rg = w >> 1;       // row group (0..1)
  const int rbase = mblk * 64 + rg * 32;
  const int row0 = rbase + lr;
  const int row1 = rbase + 16 + lr;
  const float c1_0 = wsf[S1_OFF + row0];
  const float c1_1 = wsf[S1_OFF + row1];
  const float s2ref = side ? wsf[SCAL_OFF + 1] : wsf[SCAL_OFF];
  const float sgn = side ? -1.0f : 1.0f;
  float tt0 = c1_0 + s2ref; const float so0 = sgn * fmaxf(tt0, ALPHA * tt0);
  float tt1 = c1_1 + s2ref; const float so1 = sgn * fmaxf(tt1, ALPHA * tt1);
  const int kcnt = NROW / nsplit;
  const int k0 = ks * kcnt;
  const int ksteps = kcnt >> 5;
  const int tb0 = k0 >> 5;
  const uint32_t* mr0 = amask + (size_t)row0 * 256;
  const uint32_t* mr1 = amask + (size_t)row1 * 256;
  f32x4 acc0[19], acc1[19];
  const f32x4 zero = {0.f, 0.f, 0.f, 0.f};
  #pragma unroll
  for (int ct = 0; ct < 19; ct++) { acc0[ct] = zero; acc1[ct] = zero; }

  auto STAGE = [&](int b, int tb) {   // 10 x 1KB global_load_lds per wave
    const char* tile = (const char*)(pqb + (size_t)tb * 20480);
    char* dst = (char*)Bsm[b];
    #pragma unroll
    for (int it = 0; it < 10; it++) {
      const int off = (w * 10 + it) * 1024;
      __builtin_amdgcn_global_load_lds(
          (const __attribute__((address_space(1))) void*)(tile + off + lane * 16),
          (__attribute__((address_space(3))) void*)(dst + off),
          16, 0, 0);
    }
  };

  // prologue: STAGE(0) [10], regs(0) [4]
  STAGE(0, tb0);
  uint32_t cM0 = mr0[tb0];
  uint32_t cM1 = mr1[tb0];
  const int kw0 = k0 + lg * 8;
  float4 cS0 = *(const float4*)(wsf + S2_OFF + kw0);
  float4 cS1 = *(const float4*)(wsf + S2_OFF + kw0 + 4);

  for (int s = 0; s < ksteps; s++) {
    // B: prefetch regs for step s+1 (clamped) -- 4 VMEM ops
    const int sp = (s + 1 < ksteps) ? s + 1 : s;
    const uint32_t nM0 = mr0[tb0 + sp];
    const uint32_t nM1 = mr1[tb0 + sp];
    const int kwn = k0 + sp * 32 + lg * 8;
    const float4 nS0 = *(const float4*)(wsf + S2_OFF + kwn);
    const float4 nS1 = *(const float4*)(wsf + S2_OFF + kwn + 4);

    // certify STAGE(s)+regs(s) complete; regs(s+1) stay in flight
    asm volatile("s_waitcnt vmcnt(4)" ::: "memory");
    __builtin_amdgcn_sched_barrier(0);
    __builtin_amdgcn_s_barrier();   // buf[s&1] fully written; buf[(s+1)&1] reads done

    // A: stage tile s+1 into buf[(s+1)&1] -- 10 VMEM ops (lands during compute)
    STAGE((s + 1) & 1, tb0 + sp);

    // C: exp/mask/pack for current step (register-only inputs)
    float se[8] = {cS0.x, cS0.y, cS0.z, cS0.w, cS1.x, cS1.y, cS1.z, cS1.w};
    const uint32_t b0 = (cM0 >> (lg * 8)) & 0xffu;
    const uint32_t b1 = (cM1 >> (lg * 8)) & 0xffu;
    HPack up0, up1;
    #pragma unroll
    for (int e = 0; e < 8; e += 2) {
      float e0a = c1_0 + se[e];     e0a = fmaxf(e0a, ALPHA * e0a);
      float e0b = c1_0 + se[e + 1]; e0b = fmaxf(e0b, ALPHA * e0b);
      float e1a = c1_1 + se[e];     e1a = fmaxf(e1a, ALPHA * e1a);
      float e1b = c1_1 + se[e + 1]; e1b = fmaxf(e1b, ALPHA * e1b);
      float p0a = exp2f(__builtin_fmaf(sgn, e0a, -so0)); p0a = (b0 & (1u << e)) ? p0a : 0.0f;
      float p0b = exp2f(__builtin_fmaf(sgn, e0b, -so0)); p0b = (b0 & (2u << e)) ? p0b : 0.0f;
      float p1a = exp2f(__builtin_fmaf(sgn, e1a, -so1)); p1a = (b1 & (1u << e)) ? p1a : 0.0f;
      float p1b = exp2f(__builtin_fmaf(sgn, e1b, -so1)); p1b = (b1 & (2u << e)) ? p1b : 0.0f;
      up0.h2[e >> 1] = __builtin_amdgcn_cvt_pkrtz(p0a, p0b);
      up1.h2[e >> 1] = __builtin_amdgcn_cvt_pkrtz(p1a, p1b);
    }

    const char* half = (const char*)Bsm[s & 1] + side * 20480;
    __builtin_amdgcn_s_setprio(1);   // T5: co-resident block's waves yield to MFMA
    #pragma unroll
    for (int ct = 0; ct < 19; ct++) {
      const int col = ct * 16 + lr;
      const int gp = swz(col, lg);
      f16x8 b = *(const f16x8*)(half + col * 64 + gp * 16);
      acc0[ct] = __builtin_amdgcn_mfma_f32_16x16x32_f16(up0.v, b, acc0[ct], 0, 0, 0);
      acc1[ct] = __builtin_amdgcn_mfma_f32_16x16x32_f16(up1.v, b, acc1[ct], 0, 0, 0);
    }
    __builtin_amdgcn_s_setprio(0);

    cM0 = nM0; cM1 = nM1; cS0 = nS0; cS1 = nS1;
  }

  // C/D layout: col = lane&15, row = lg*4 + reg (per frag)
  float* pb = part + ((size_t)ks * NROW + rbase) * 608 + (size_t)side * 304;
  #pragma unroll
  for (int ct = 0; ct < 19; ct++) {
    const int col = ct * 16 + lr;
    #pragma unroll
    for (int r = 0; r < 4; r++) {
      pb[(size_t)(lg * 4 + r) * 608 + col] = acc0[ct][r];
      pb[(size_t)(16 + lg * 4 + r) * 608 + col] = acc1[ct][r];
    }
  }
}

// ---------------- K5: reduce k-splits, normalize, elu ----------------
__global__ void k_final(const float* __restrict__ part, float* __restrict__ out, int nsplit) {
  const int i = blockIdx.x;
  const int t = threadIdx.x;
  if (t >= 300) return;
  float sp = 0.f, sn = 0.f, zp = 0.f, zn = 0.f;
  for (int s = 0; s < nsplit; s++) {
    const float* p = part + ((size_t)s * NROW + i) * 608;
    sp += p[t];
    sn += p[304 + t];
    zp += p[300];
    zn += p[604];
  }
  float x = sp / zp - sn / zn;
  out[(size_t)i * 300 + t] = (x > 0.f) ? x : (exp2f(x * LOG2E) - 1.0f);
}

extern "C" void kernel_launch(void* const* d_in, const int* in_sizes, int n_in,
                              void* d_out, int out_size, void* d_ws, size_t ws_size,
                              hipStream_t stream) {
  const float* inp = (const float*)d_in[0];
  const int* adj = (const int*)d_in[1];
  const float* Wm = (const float*)d_in[2];
  const float* a = (const float*)d_in[3];
  const float* wt = (const float*)d_in[4];
  float* out = (float*)d_out;
  float* wsf = (float*)d_ws;
  uint16_t* pqb = (uint16_t*)((char*)d_ws + PQB_OFF);
  uint32_t* amask = (uint32_t*)((char*)d_ws + AMSK_OFF);
  uint16_t* wtf = (uint16_t*)((char*)d_ws + WTF_OFF);
  float* part = (float*)((char*)d_ws + PART_OFF);

  int nsplit = 4;
  while (nsplit > 1 &&
         (size_t)PART_OFF + (size_t)nsplit * NROW * 608 * 4 > ws_size)
    nsplit >>= 1;

  const int pack_blocks = (NROW * 256 + 639) / 640;
  k_wa<<<75, 256, 0, stream>>>(Wm, a, wsf);
  k_wprep<<<20, 320, 0, stream>>>(wt, wtf);
  k_s12<<<NROW / 4, 256, 0, stream>>>(inp, wsf);
  k_minmax<<<1, 1024, 0, stream>>>(wsf);
  k_packwt<<<WT_BLOCKS + pack_blocks, 640, 0, stream>>>(adj, amask, inp, wtf, pqb);
  k_main<<<128 * nsplit, 256, 0, stream>>>(amask, wsf, pqb, part, nsplit);
  k_final<<<NROW, 320, 0, stream>>>(part, out, nsplit);
}